// Round 8
// baseline (518.708 us; speedup 1.0000x reference)
//
#include <hip/hip_runtime.h>
#include <hip/hip_bf16.h>

// Basic_Transformer on MI355X (gfx950): bf16 MFMA pipeline.
// B=2 S=2048 C=512 L=4 H=8 CH=64 OD=256; rows M = B*S = 4096.

typedef __bf16 bf16_t;
typedef __attribute__((ext_vector_type(8))) __bf16 bf16x8;
typedef __attribute__((ext_vector_type(4))) __bf16 bf16x4;
typedef __attribute__((ext_vector_type(4))) float f32x4;

#define MROWS 4096
#define KVSPLIT 2
#define NT 16   // (2048/KVSPLIT)/64 kv tiles per split

static __device__ __forceinline__ void gload_lds16(const void* g, void* l) {
  __builtin_amdgcn_global_load_lds((const __attribute__((address_space(1))) void*)g,
                                   (__attribute__((address_space(3))) void*)l, 16, 0, 0);
}
static __device__ __forceinline__ float fexp2(float x) {
  float r;
  asm("v_exp_f32 %0, %1" : "=v"(r) : "v"(x));
  return r;
}

// ---------------- layernorm: one wave per row (64 lanes x 8 f32) ----------------
__global__ __launch_bounds__(256) void ln_kernel(const float* __restrict__ xin,
    const float* __restrict__ gamma, const float* __restrict__ beta,
    bf16_t* __restrict__ hout)
{
  int w = threadIdx.x >> 6, l = threadIdx.x & 63;
  int row = blockIdx.x * 4 + w;
  const float* xr = xin + (size_t)row * 512 + l * 8;
  f32x4 a = *(const f32x4*)xr;
  f32x4 b2 = *(const f32x4*)(xr + 4);
  float s = a[0]+a[1]+a[2]+a[3]+b2[0]+b2[1]+b2[2]+b2[3];
  #pragma unroll
  for (int m = 1; m < 64; m <<= 1) s += __shfl_xor(s, m, 64);
  float mu = s * (1.0f/512.0f);
  float vs = 0.f;
  #pragma unroll
  for (int i = 0; i < 4; i++) { float d = a[i]-mu; vs += d*d; d = b2[i]-mu; vs += d*d; }
  #pragma unroll
  for (int m = 1; m < 64; m <<= 1) vs += __shfl_xor(vs, m, 64);
  float rstd = rsqrtf(vs * (1.0f/512.0f) + 1e-5f);
  const float* gp = gamma + l*8;
  const float* bp = beta + l*8;
  f32x4 g0 = *(const f32x4*)gp, g1 = *(const f32x4*)(gp+4);
  f32x4 p0 = *(const f32x4*)bp, p1 = *(const f32x4*)(bp+4);
  bf16x8 h;
  #pragma unroll
  for (int i = 0; i < 4; i++) {
    h[i]   = (bf16_t)((a[i]-mu)*rstd*g0[i] + p0[i]);
    h[4+i] = (bf16_t)((b2[i]-mu)*rstd*g1[i] + p1[i]);
  }
  *(bf16x8*)(hout + (size_t)row*512 + l*8) = h;
}

// ---------------- weight transpose + cast: [K][N] f32 -> [N][K] bf16 ----------------
__global__ __launch_bounds__(256) void prep_kernel(
    const float* __restrict__ Wq, const float* __restrict__ Wk, const float* __restrict__ Wv,
    const float* __restrict__ Wo, const float* __restrict__ Wg, const float* __restrict__ Wf,
    bf16_t* __restrict__ WqkvT, bf16_t* __restrict__ WoT,
    bf16_t* __restrict__ WgT, bf16_t* __restrict__ WfT)
{
  __shared__ float tile[32][33];
  int z = blockIdx.z;
  const float* src; bf16_t* dst; int K = 512, N = 512;
  if (z < 12) {
    int lay = z & 3, which = z >> 2;  // 0..3:Wq 4..7:Wk 8..11:Wv
    src = (which == 0 ? Wq : which == 1 ? Wk : Wv) + (size_t)lay*512*512;
    dst = WqkvT + (size_t)lay*1536*512 + (size_t)which*512*512;
  } else if (z < 16) {
    src = Wo + (size_t)(z-12)*512*512;
    dst = WoT + (size_t)(z-12)*512*512;
  } else if (z == 16) { src = Wg; dst = WgT; }
  else { src = Wf; dst = WfT; K = 256; }
  int k0 = blockIdx.y*32, n0 = blockIdx.x*32;
  if (k0 >= K) return;  // uniform per block (Wf has K=256)
  int tx = threadIdx.x & 31, ty = threadIdx.x >> 5;
  #pragma unroll
  for (int j = 0; j < 4; j++)
    tile[ty + j*8][tx] = src[(size_t)(k0 + ty + j*8)*N + n0 + tx];
  __syncthreads();
  #pragma unroll
  for (int j = 0; j < 4; j++)
    dst[(size_t)(n0 + ty + j*8)*K + k0 + tx] = (bf16_t)tile[tx][ty + j*8];
}

// ---------------- GEMM: C[M x N] = A[M x K](bf16) * Bt[N x K](bf16)^T ----------------
// BM x 128 tile, BK=64, 4 waves (2x2 of BM/2 x 64), 16x16x32 bf16 MFMA.
// 1-D grid with XCD-aware swizzle (each XCD owns a contiguous by-range).
// EPI 0: QKV. q (col<512, *qscale) -> qbuf[row][512];
//        k (512..1023) -> kT[b][h][tile][kv][ch] (8KB tiles);
//        v (>=1024)    -> vT[b][h][tile][ch][kv] (8KB tiles).
// EPI 1: f32 out + bias + resid.  EPI 2: f32 out + bias.
template<int EPI, int BM, int NX>
__global__ __launch_bounds__(256) void gemm_bt(
    const bf16_t* __restrict__ A, const bf16_t* __restrict__ Bt,
    int N, int K,
    void* __restrict__ Cout, bf16_t* __restrict__ kTout, bf16_t* __restrict__ vTout,
    const float* __restrict__ bias, const float* __restrict__ resid, float qscale)
{
  __shared__ bf16_t As[BM*64];
  __shared__ bf16_t Bs[128*64];
  constexpr int MF = BM/32;              // M-fragments per wave (128->4, 64->2)
  int cpx = gridDim.x >> 3;
  int logical = (blockIdx.x & 7) * cpx + (blockIdx.x >> 3);
  int bx = logical % NX, by = logical / NX;
  int t = threadIdx.x, w = t >> 6, l = t & 63;
  int tm = by * BM, tn = bx * 128;
  int wm = (w >> 1) * (BM/2), wn = (w & 1) * 64;
  f32x4 acc[MF][4] = {};
  int srow = l >> 3;                    // staging: 8 rows per 1KB inst
  int schunk = ((l & 7) ^ srow) * 8;    // XOR-swizzle via pre-swizzled global source
  for (int k0 = 0; k0 < K; k0 += 64) {
    __syncthreads();
    #pragma unroll
    for (int i = 0; i < BM/32; i++) {
      int rb = i*32 + w*8;
      gload_lds16(A + (size_t)(tm + rb + srow)*K + k0 + schunk, &As[rb*64]);
    }
    #pragma unroll
    for (int i = 0; i < 4; i++) {
      int rb = i*32 + w*8;
      gload_lds16(Bt + (size_t)(tn + rb + srow)*K + k0 + schunk, &Bs[rb*64]);
    }
    __syncthreads();
    #pragma unroll
    for (int kk = 0; kk < 2; kk++) {
      bf16x8 af[MF], bfr[4];
      #pragma unroll
      for (int mf = 0; mf < MF; mf++) {
        int row = wm + mf*16 + (l & 15);
        int off = (kk*32 + (l >> 4)*8) ^ ((row & 7) << 3);
        af[mf] = *(const bf16x8*)&As[row*64 + off];
      }
      #pragma unroll
      for (int nf = 0; nf < 4; nf++) {
        int row = wn + nf*16 + (l & 15);
        int off = (kk*32 + (l >> 4)*8) ^ ((row & 7) << 3);
        bfr[nf] = *(const bf16x8*)&Bs[row*64 + off];
      }
      #pragma unroll
      for (int mf = 0; mf < MF; mf++)
        #pragma unroll
        for (int nf = 0; nf < 4; nf++)
          acc[mf][nf] = __builtin_amdgcn_mfma_f32_16x16x32_bf16(af[mf], bfr[nf], acc[mf][nf], 0, 0, 0);
    }
  }
  int colb = tn + wn + (l & 15);
  int rowb = tm + wm + ((l >> 4) << 2);
  if (EPI == 0 && tn >= 1024) {
    // v -> vT[b][h][tile][ch][kv], vectorized over 4 consecutive s (same tile)
    #pragma unroll
    for (int mf = 0; mf < MF; mf++)
      #pragma unroll
      for (int nf = 0; nf < 4; nf++) {
        int col = colb + nf*16;
        int hh = (col - 1024) >> 6, ch = (col - 1024) & 63;
        int row = rowb + mf*16;
        int bb = row >> 11, sin = row & 2047;
        bf16x4 pk;
        #pragma unroll
        for (int r = 0; r < 4; r++) pk[r] = (bf16_t)acc[mf][nf][r];
        *(bf16x4*)&vTout[(((size_t)(bb*8 + hh)*32 + (sin >> 6))*64 + ch)*64 + (sin & 63)] = pk;
      }
    return;
  }
  if (EPI == 0 && tn >= 512) {
    // k -> kT[b][h][tile][kv][ch] (scalar stores, rows stride 64 ch-el)
    #pragma unroll
    for (int mf = 0; mf < MF; mf++)
      #pragma unroll
      for (int nf = 0; nf < 4; nf++) {
        int col = colb + nf*16;
        int hh = (col - 512) >> 6, ch = (col - 512) & 63;
        int row = rowb + mf*16;
        int bb = row >> 11, sin = row & 2047;
        size_t base = (((size_t)(bb*8 + hh)*32 + (sin >> 6))*64 + (sin & 63))*64 + ch;
        #pragma unroll
        for (int r = 0; r < 4; r++)
          kTout[base + (size_t)r*64] = (bf16_t)acc[mf][nf][r];
      }
    return;
  }
  #pragma unroll
  for (int mf = 0; mf < MF; mf++)
    #pragma unroll
    for (int nf = 0; nf < 4; nf++)
      #pragma unroll
      for (int r = 0; r < 4; r++) {
        int row = rowb + mf*16 + r;
        int col = colb + nf*16;
        float v = acc[mf][nf][r];
        if (EPI == 0) {
          ((bf16_t*)Cout)[(size_t)row*512 + col] = (bf16_t)(v * qscale);
        } else if (EPI == 1) {
          ((float*)Cout)[(size_t)row*N + col] = v + bias[col] + resid[(size_t)row*N + col];
        } else {
          ((float*)Cout)[(size_t)row*N + col] = v + bias[col];
        }
      }
}

// ---------------- fused flash attention (no-max softmax, KV-split partials) --------
// 1-D grid 1024, XCD-swizzled: each (h,b,sp) group's 32 q0-blocks share one XCD.
// 256 threads = 4 waves; wave w owns q-rows w*16..+15.
// qbuf: [B*S][512] bf16 (q, pre-scaled by 0.125*log2e).
// kT/vT: [B][H][32 tiles][8KB] — kT tile [kv][ch], vT tile [ch][kv].
// K double-buffered in LDS (one barrier per tile); V fragments direct
// global->reg (coalescible in tiled layout), issued a phase early.
// Partials: Ows bf16 [sp][4096][512], lws f32 [sp][4096][8].
__global__ __launch_bounds__(256) void attn_kernel(const bf16_t* __restrict__ qbuf,
                                                   const bf16_t* __restrict__ kT,
                                                   const bf16_t* __restrict__ vT,
                                                   bf16_t* __restrict__ Ows,
                                                   float* __restrict__ lws)
{
  __shared__ bf16_t Ks[2][64*64];   // K tile [kv][ch] dbuf, swizzled
  __shared__ bf16_t Ps[4*16*72];    // per-wave P, stride 72
  int t = threadIdx.x, w = t >> 6, l = t & 63;
  int logical = (blockIdx.x & 7) * 128 + (blockIdx.x >> 3);
  int q0 = (logical & 31) * 64;
  int group = logical >> 5;            // 0..31
  int h = group & 7;
  int bz = group >> 3;
  int b = bz >> 1, sp = bz & 1;
  size_t rbase = (size_t)b * 2048;
  int lq = l & 15, hi = l >> 4;
  int srow = l >> 3;
  int schunk = ((l & 7) ^ srow) * 8;
  int rb0 = w*16, rb1 = w*16 + 8;
  size_t tbase = ((size_t)(b*8 + h)*32 + sp*16) * 4096;  // first 8KB tile of split
  const bf16_t* kb = kT + tbase;
  const bf16_t* vb = vT + tbase + (size_t)lq*64 + hi*8;  // per-lane V frag base
  // Q fragments direct from global (pre-scaled); uncoalesced but once
  const bf16_t* qp = qbuf + (rbase + q0 + w*16 + lq)*512 + h*64 + hi*8;
  bf16x8 aq0 = *(const bf16x8*)qp;
  bf16x8 aq1 = *(const bf16x8*)(qp + 32);
  // prologue: stage K tile 0
  gload_lds16(kb + (size_t)(rb0 + srow)*64 + schunk, &Ks[0][rb0*64]);
  gload_lds16(kb + (size_t)(rb1 + srow)*64 + schunk, &Ks[0][rb1*64]);
  asm volatile("s_waitcnt vmcnt(0)" ::: "memory");
  __builtin_amdgcn_s_barrier();

  int pw = w * 16 * 72;
  f32x4 accO[4] = {};
  f32x4 lacc = {};
  bf16x8 ones;
  #pragma unroll
  for (int e = 0; e < 8; e++) ones[e] = (bf16_t)1.0f;
  int swz = (lq & 7) << 3;

  for (int tt = 0; tt < NT; ++tt) {
    int cur = tt & 1;
    // issue V(t) fragment loads (regs) + stage K(t+1) (LDS, other buffer)
    bf16x8 vv[8];
    const bf16_t* vt0 = vb + (size_t)tt*4096;
    #pragma unroll
    for (int nf = 0; nf < 4; nf++) {
      vv[nf]   = *(const bf16x8*)(vt0 + nf*1024);
      vv[4+nf] = *(const bf16x8*)(vt0 + nf*1024 + 32);
    }
    if (tt < NT-1) {
      const bf16_t* kn = kb + (size_t)(tt+1)*4096;
      gload_lds16(kn + (size_t)(rb0 + srow)*64 + schunk, &Ks[cur^1][rb0*64]);
      gload_lds16(kn + (size_t)(rb1 + srow)*64 + schunk, &Ks[cur^1][rb1*64]);
    }
    __builtin_amdgcn_sched_barrier(0);  // keep loads issued above compute
    // QK from Ks[cur] + aq regs
    f32x4 s4[4] = {};
    __builtin_amdgcn_s_setprio(1);
    #pragma unroll
    for (int kk = 0; kk < 2; kk++) {
      int off = (kk*32 + hi*8) ^ swz;
      bf16x8 aq = kk ? aq1 : aq0;
      #pragma unroll
      for (int nf = 0; nf < 4; nf++) {
        bf16x8 bk = *(const bf16x8*)&Ks[cur][(nf*16 + lq)*64 + off];
        s4[nf] = __builtin_amdgcn_mfma_f32_16x16x32_bf16(aq, bk, s4[nf], 0, 0, 0);
      }
    }
    __builtin_amdgcn_s_setprio(0);
    // P = 2^S -> Ps (wave-private)
    #pragma unroll
    for (int nf = 0; nf < 4; nf++)
      #pragma unroll
      for (int r = 0; r < 4; r++)
        Ps[pw + (hi*4 + r)*72 + nf*16 + lq] = (bf16_t)fexp2(s4[nf][r]);
    // PV + row-sum (compiler inserts the vv/Ps waits it needs)
    __builtin_amdgcn_s_setprio(1);
    #pragma unroll
    for (int kk = 0; kk < 2; kk++) {
      bf16x8 pa = *(const bf16x8*)&Ps[pw + lq*72 + kk*32 + hi*8];
      lacc = __builtin_amdgcn_mfma_f32_16x16x32_bf16(pa, ones, lacc, 0, 0, 0);
      #pragma unroll
      for (int nf = 0; nf < 4; nf++)
        accO[nf] = __builtin_amdgcn_mfma_f32_16x16x32_bf16(pa, vv[kk*4+nf], accO[nf], 0, 0, 0);
    }
    __builtin_amdgcn_s_setprio(0);
    if (tt < NT-1) {
      // one barrier per tile: K(t+1) landed (vmcnt) AND all Ks[cur] reads done (lgkm)
      asm volatile("s_waitcnt vmcnt(0) lgkmcnt(0)" ::: "memory");
      __builtin_amdgcn_s_barrier();
    }
  }
  // store bf16 partials (no normalize; combine does it)
  bf16_t* op = Ows + (size_t)sp*MROWS*512 + (rbase + q0 + w*16 + hi*4)*512 + h*64 + lq;
  #pragma unroll
  for (int nf = 0; nf < 4; nf++)
    #pragma unroll
    for (int r = 0; r < 4; r++)
      op[(size_t)r*512 + nf*16] = (bf16_t)accO[nf][r];
  if (lq == 0) {
    size_t rowb = rbase + q0 + w*16 + hi*4;
    #pragma unroll
    for (int r = 0; r < 4; r++)
      lws[(size_t)sp*MROWS*8 + (rowb + r)*8 + h] = lacc[r];
  }
}

// ---------------- combine: obuf = (sum_sp Ows) / (sum_sp lws) ----------------
__global__ __launch_bounds__(256) void combine_kernel(const bf16_t* __restrict__ Ows,
                                                      const float* __restrict__ lws,
                                                      bf16_t* __restrict__ obuf)
{
  int idx = blockIdx.x * 256 + threadIdx.x;   // 4096*512/4 = 524288 threads
  int row = idx >> 7, c4 = (idx & 127) * 4;
  bf16x4 o0 = *(const bf16x4*)&Ows[(size_t)row*512 + c4];
  bf16x4 o1 = *(const bf16x4*)&Ows[(size_t)(MROWS + row)*512 + c4];
  int h = c4 >> 6;
  float li = 1.0f / (lws[row*8 + h] + lws[MROWS*8 + row*8 + h]);
  bf16x4 o;
  #pragma unroll
  for (int i = 0; i < 4; i++) o[i] = (bf16_t)(((float)o0[i] + (float)o1[i]) * li);
  *(bf16x4*)&obuf[(size_t)row*512 + c4] = o;
}

// ---------------- gated gelu: ff = a * gelu(gate), g already has +bg ----------------
__global__ __launch_bounds__(256) void gelu_kernel(const float* __restrict__ g,
                                                   bf16_t* __restrict__ ff)
{
  int idx = blockIdx.x * 256 + threadIdx.x;  // 262144 threads, 4 outputs each
  int row = idx >> 6;
  int c = (idx & 63) * 4;
  const float* gr = g + (size_t)row*512;
  f32x4 a = *(const f32x4*)(gr + c);
  f32x4 u = *(const f32x4*)(gr + 256 + c);
  bf16x4 o4;
  #pragma unroll
  for (int i = 0; i < 4; i++) {
    float x = u[i];
    float tt = tanhf(0.7978845608f * x * (1.0f + 0.044715f * x * x));
    o4[i] = (bf16_t)(a[i] * 0.5f * x * (1.0f + tt));
  }
  *(bf16x4*)(ff + (size_t)row*256 + c) = o4;
}

// ---------------- launcher ----------------
extern "C" void kernel_launch(void* const* d_in, const int* in_sizes, int n_in,
                              void* d_out, int out_size, void* d_ws, size_t ws_size,
                              hipStream_t stream)
{
  const float* x     = (const float*)d_in[0];
  const float* gamma = (const float*)d_in[1];
  const float* beta  = (const float*)d_in[2];
  const float* Wq    = (const float*)d_in[3];
  const float* Wk    = (const float*)d_in[4];
  const float* Wv    = (const float*)d_in[5];
  const float* Wo    = (const float*)d_in[6];
  const float* bo    = (const float*)d_in[7];
  const float* Wg    = (const float*)d_in[8];
  const float* bg    = (const float*)d_in[9];
  const float* Wf    = (const float*)d_in[10];
  const float* bf    = (const float*)d_in[11];

  char* ws = (char*)d_ws;
  float*  xcur  = (float*)ws;                            // 0-8 MB   f32 [4096][512]
  bf16_t* hbuf  = (bf16_t*)(ws + (8u<<20));              // 8-12 MB  bf16 [4096][512]
  bf16_t* qbuf  = (bf16_t*)(ws + (12u<<20));             // 12-16 MB bf16 [4096][512]
  bf16_t* kTb   = (bf16_t*)(ws + (16u<<20));             // 16-20 MB bf16 [2][8][32][64][64]
  bf16_t* vTb   = (bf16_t*)(ws + (20u<<20));             // 20-24 MB bf16 [2][8][32][64][64]
  bf16_t* obuf  = (bf16_t*)(ws + (24u<<20));             // 24-28 MB bf16 [4096][512]
  bf16_t* WqkvT = (bf16_t*)(ws + (28u<<20));             // 28-34 MB
  bf16_t* WoT   = (bf16_t*)(ws + (34u<<20));             // 34-36 MB
  bf16_t* WgT   = (bf16_t*)(ws + (36u<<20));             // 0.5 MB
  bf16_t* WfT   = (bf16_t*)(ws + (36u<<20) + (512u<<10));// 0.25 MB
  float*  lws   = (float*)(ws + (37u<<20));              // 37-37.25 MB f32 [2][4096][8]
  bf16_t* Ows   = (bf16_t*)(ws + (40u<<20));             // 40-48 MB bf16 [2][4096][512]
  float*  gbuf  = (float*)(ws + (40u<<20));              // reuse Ows region in MLP (f32 8MB)
  bf16_t* ffb   = obuf;                                  // reuse (o dead by MLP)

  const float QSCALE = 0.125f * 1.44269504f;  // fold 1/sqrt(CH) and log2(e) into q

  prep_kernel<<<dim3(16,16,18), 256, 0, stream>>>(Wq,Wk,Wv,Wo,Wg,Wf,WqkvT,WoT,WgT,WfT);
  hipMemcpyAsync(xcur, x, (size_t)MROWS*512*4, hipMemcpyDeviceToDevice, stream);

  for (int lay = 0; lay < 4; lay++) {
    ln_kernel<<<1024, 256, 0, stream>>>(xcur, gamma + lay*512, beta + lay*512, hbuf);
    gemm_bt<0,64,12><<<768, 256, 0, stream>>>(hbuf, WqkvT + (size_t)lay*1536*512,
                                              1536, 512, qbuf, kTb, vTb, nullptr, nullptr, QSCALE);
    attn_kernel<<<1024, 256, 0, stream>>>(qbuf, kTb, vTb, Ows, lws);
    combine_kernel<<<2048, 256, 0, stream>>>(Ows, lws, obuf);
    gemm_bt<1,64,4><<<256, 256, 0, stream>>>(obuf, WoT + (size_t)lay*512*512,
                                             512, 512, xcur, nullptr, nullptr, bo + lay*512, xcur, 1.0f);
  }
  ln_kernel<<<1024, 256, 0, stream>>>(xcur, gamma + 4*512, beta + 4*512, hbuf);
  gemm_bt<2,64,4><<<256, 256, 0, stream>>>(hbuf, WgT, 512, 512, gbuf, nullptr, nullptr, bg, nullptr, 1.0f);
  gelu_kernel<<<1024, 256, 0, stream>>>(gbuf, ffb);
  gemm_bt<1,64,4><<<256, 256, 0, stream>>>(ffb, WfT, 512, 256, d_out, nullptr, nullptr, bf, xcur, 1.0f);
}

// Round 9
// 401.888 us; speedup vs baseline: 1.2907x; 1.2907x over previous
//
#include <hip/hip_runtime.h>
#include <hip/hip_bf16.h>

// Basic_Transformer on MI355X (gfx950): bf16 MFMA pipeline.
// B=2 S=2048 C=512 L=4 H=8 CH=64 OD=256; rows M = B*S = 4096.

typedef __bf16 bf16_t;
typedef __attribute__((ext_vector_type(8))) __bf16 bf16x8;
typedef __attribute__((ext_vector_type(4))) __bf16 bf16x4;
typedef __attribute__((ext_vector_type(4))) float f32x4;

#define MROWS 4096
#define KVSPLIT 2
#define NT 16   // (2048/KVSPLIT)/64 kv tiles per split

static __device__ __forceinline__ void gload_lds16(const void* g, void* l) {
  __builtin_amdgcn_global_load_lds((const __attribute__((address_space(1))) void*)g,
                                   (__attribute__((address_space(3))) void*)l, 16, 0, 0);
}
static __device__ __forceinline__ float fexp2(float x) {
  float r;
  asm("v_exp_f32 %0, %1" : "=v"(r) : "v"(x));
  return r;
}

// ---------------- layernorm: one wave per row (64 lanes x 8 f32) ----------------
__global__ __launch_bounds__(256) void ln_kernel(const float* __restrict__ xin,
    const float* __restrict__ gamma, const float* __restrict__ beta,
    bf16_t* __restrict__ hout)
{
  int w = threadIdx.x >> 6, l = threadIdx.x & 63;
  int row = blockIdx.x * 4 + w;
  const float* xr = xin + (size_t)row * 512 + l * 8;
  f32x4 a = *(const f32x4*)xr;
  f32x4 b2 = *(const f32x4*)(xr + 4);
  float s = a[0]+a[1]+a[2]+a[3]+b2[0]+b2[1]+b2[2]+b2[3];
  #pragma unroll
  for (int m = 1; m < 64; m <<= 1) s += __shfl_xor(s, m, 64);
  float mu = s * (1.0f/512.0f);
  float vs = 0.f;
  #pragma unroll
  for (int i = 0; i < 4; i++) { float d = a[i]-mu; vs += d*d; d = b2[i]-mu; vs += d*d; }
  #pragma unroll
  for (int m = 1; m < 64; m <<= 1) vs += __shfl_xor(vs, m, 64);
  float rstd = rsqrtf(vs * (1.0f/512.0f) + 1e-5f);
  const float* gp = gamma + l*8;
  const float* bp = beta + l*8;
  f32x4 g0 = *(const f32x4*)gp, g1 = *(const f32x4*)(gp+4);
  f32x4 p0 = *(const f32x4*)bp, p1 = *(const f32x4*)(bp+4);
  bf16x8 h;
  #pragma unroll
  for (int i = 0; i < 4; i++) {
    h[i]   = (bf16_t)((a[i]-mu)*rstd*g0[i] + p0[i]);
    h[4+i] = (bf16_t)((b2[i]-mu)*rstd*g1[i] + p1[i]);
  }
  *(bf16x8*)(hout + (size_t)row*512 + l*8) = h;
}

// ---------------- weight transpose + cast: [K][N] f32 -> [N][K] bf16 ----------------
__global__ __launch_bounds__(256) void prep_kernel(
    const float* __restrict__ Wq, const float* __restrict__ Wk, const float* __restrict__ Wv,
    const float* __restrict__ Wo, const float* __restrict__ Wg, const float* __restrict__ Wf,
    bf16_t* __restrict__ WqkvT, bf16_t* __restrict__ WoT,
    bf16_t* __restrict__ WgT, bf16_t* __restrict__ WfT)
{
  __shared__ float tile[32][33];
  int z = blockIdx.z;
  const float* src; bf16_t* dst; int K = 512, N = 512;
  if (z < 12) {
    int lay = z & 3, which = z >> 2;  // 0..3:Wq 4..7:Wk 8..11:Wv
    src = (which == 0 ? Wq : which == 1 ? Wk : Wv) + (size_t)lay*512*512;
    dst = WqkvT + (size_t)lay*1536*512 + (size_t)which*512*512;
  } else if (z < 16) {
    src = Wo + (size_t)(z-12)*512*512;
    dst = WoT + (size_t)(z-12)*512*512;
  } else if (z == 16) { src = Wg; dst = WgT; }
  else { src = Wf; dst = WfT; K = 256; }
  int k0 = blockIdx.y*32, n0 = blockIdx.x*32;
  if (k0 >= K) return;  // uniform per block (Wf has K=256)
  int tx = threadIdx.x & 31, ty = threadIdx.x >> 5;
  #pragma unroll
  for (int j = 0; j < 4; j++)
    tile[ty + j*8][tx] = src[(size_t)(k0 + ty + j*8)*N + n0 + tx];
  __syncthreads();
  #pragma unroll
  for (int j = 0; j < 4; j++)
    dst[(size_t)(n0 + ty + j*8)*K + k0 + tx] = (bf16_t)tile[tx][ty + j*8];
}

// ---------------- GEMM: C[M x N] = A[M x K](bf16) * Bt[N x K](bf16)^T ----------------
// BM x 128 tile, BK=64, 4 waves (2x2 of BM/2 x 64), 16x16x32 bf16 MFMA.
// 1-D grid (NX * ny blocks) with XCD-aware swizzle: each XCD owns a contiguous
// run of `by` values (A-panel L2 reuse), B panels small enough to replicate.
// EPI 0: QKV. cols<512 (q) scaled by qscale -> qkv[row][1024]; cols 512..1023 (k)
//        plain -> qkv; cols>=1024 (v) -> vT[b][h][ch][2048] (pre-transposed).
// EPI 1: f32 out + bias + resid.  EPI 2: f32 out + bias.
template<int EPI, int BM, int NX>
__global__ __launch_bounds__(256) void gemm_bt(
    const bf16_t* __restrict__ A, const bf16_t* __restrict__ Bt,
    int N, int K,
    void* __restrict__ Cout, bf16_t* __restrict__ vTout,
    const float* __restrict__ bias, const float* __restrict__ resid, float qscale)
{
  __shared__ bf16_t As[BM*64];
  __shared__ bf16_t Bs[128*64];
  constexpr int MF = BM/32;              // M-fragments per wave (128->4, 64->2)
  int cpx = gridDim.x >> 3;
  int logical = (blockIdx.x & 7) * cpx + (blockIdx.x >> 3);
  int bx = logical % NX, by = logical / NX;
  int t = threadIdx.x, w = t >> 6, l = t & 63;
  int tm = by * BM, tn = bx * 128;
  int wm = (w >> 1) * (BM/2), wn = (w & 1) * 64;
  f32x4 acc[MF][4] = {};
  int srow = l >> 3;                    // staging: 8 rows per 1KB inst
  int schunk = ((l & 7) ^ srow) * 8;    // XOR-swizzle via pre-swizzled global source
  for (int k0 = 0; k0 < K; k0 += 64) {
    __syncthreads();
    #pragma unroll
    for (int i = 0; i < BM/32; i++) {
      int rb = i*32 + w*8;
      gload_lds16(A + (size_t)(tm + rb + srow)*K + k0 + schunk, &As[rb*64]);
    }
    #pragma unroll
    for (int i = 0; i < 4; i++) {
      int rb = i*32 + w*8;
      gload_lds16(Bt + (size_t)(tn + rb + srow)*K + k0 + schunk, &Bs[rb*64]);
    }
    __syncthreads();
    #pragma unroll
    for (int kk = 0; kk < 2; kk++) {
      bf16x8 af[MF], bfr[4];
      #pragma unroll
      for (int mf = 0; mf < MF; mf++) {
        int row = wm + mf*16 + (l & 15);
        int off = (kk*32 + (l >> 4)*8) ^ ((row & 7) << 3);
        af[mf] = *(const bf16x8*)&As[row*64 + off];
      }
      #pragma unroll
      for (int nf = 0; nf < 4; nf++) {
        int row = wn + nf*16 + (l & 15);
        int off = (kk*32 + (l >> 4)*8) ^ ((row & 7) << 3);
        bfr[nf] = *(const bf16x8*)&Bs[row*64 + off];
      }
      #pragma unroll
      for (int mf = 0; mf < MF; mf++)
        #pragma unroll
        for (int nf = 0; nf < 4; nf++)
          acc[mf][nf] = __builtin_amdgcn_mfma_f32_16x16x32_bf16(af[mf], bfr[nf], acc[mf][nf], 0, 0, 0);
    }
  }
  int colb = tn + wn + (l & 15);
  int rowb = tm + wm + ((l >> 4) << 2);
  if (EPI == 0 && tn >= 1024) {
    // v region -> vT[b][h][ch][2048], vectorized over 4 consecutive s
    #pragma unroll
    for (int mf = 0; mf < MF; mf++)
      #pragma unroll
      for (int nf = 0; nf < 4; nf++) {
        int col = colb + nf*16;
        int hh = (col - 1024) >> 6, ch = (col - 1024) & 63;
        int row = rowb + mf*16;
        int bb = row >> 11, sdx = row & 2047;
        bf16x4 pk;
        #pragma unroll
        for (int r = 0; r < 4; r++) pk[r] = (bf16_t)acc[mf][nf][r];
        *(bf16x4*)&vTout[(((size_t)bb*8 + hh)*64 + ch)*2048 + sdx] = pk;
      }
    return;
  }
  #pragma unroll
  for (int mf = 0; mf < MF; mf++)
    #pragma unroll
    for (int nf = 0; nf < 4; nf++)
      #pragma unroll
      for (int r = 0; r < 4; r++) {
        int row = rowb + mf*16 + r;
        int col = colb + nf*16;
        float v = acc[mf][nf][r];
        if (EPI == 0) {
          if (col < 512) v *= qscale;
          ((bf16_t*)Cout)[(size_t)row*1024 + col] = (bf16_t)v;
        } else if (EPI == 1) {
          ((float*)Cout)[(size_t)row*N + col] = v + bias[col] + resid[(size_t)row*N + col];
        } else {
          ((float*)Cout)[(size_t)row*N + col] = v + bias[col];
        }
      }
}

// ---------------- fused flash attention (no-max softmax, KV-split partials) --------
// 1-D grid 1024, XCD-swizzled so each (h,b,sp) group's 32 q0-blocks share one XCD
// (K/V panel 256 KB -> L2-resident). 256 threads = 4 waves; wave w: q-rows w*16..+15.
// qkv: [B*S][1024] bf16: q cols 0..511 (pre-scaled by 0.125*log2e), k 512..1023.
// vT:  [B][H][64 ch][2048 s] bf16.
// K AND V double-buffered in LDS; stage(t+1) issued at tile top into buf[cur^1],
// counted vmcnt(4) gates stage(t) (issued LAST iter -> full-tile prefetch window).
// Two barriers/tile, no drains on the critical path.
// Partials: Ows bf16 [sp][4096][512], lws f32 [sp][4096][8].
__global__ __launch_bounds__(256) void attn_kernel(const bf16_t* __restrict__ qkv,
                                                   const bf16_t* __restrict__ vT,
                                                   bf16_t* __restrict__ Ows,
                                                   float* __restrict__ lws)
{
  __shared__ bf16_t Ks[2][64*64];   // K tile [kv][ch] dbuf, swizzled
  __shared__ bf16_t Vs[2][64*64];   // V^T tile [ch][kv] dbuf, swizzled
  __shared__ bf16_t Ps[4*16*72];    // per-wave P, stride 72
  int t = threadIdx.x, w = t >> 6, l = t & 63;
  // XCD swizzle: logical id contiguous per XCD; group = (h,b,sp), 4 groups/XCD.
  int logical = (blockIdx.x & 7) * 128 + (blockIdx.x >> 3);
  int q0 = (logical & 31) * 64;
  int group = logical >> 5;            // 0..31
  int h = group & 7;
  int bz = group >> 3;
  int b = bz >> 1, sp = bz & 1;
  size_t rbase = (size_t)b * 2048;
  int kvb = sp * (2048/KVSPLIT);
  int lq = l & 15, hi = l >> 4;
  int srow = l >> 3;
  int schunk = ((l & 7) ^ srow) * 8;
  int rb0 = w*16, rb1 = w*16 + 8;
  const bf16_t* kb  = qkv + rbase*1024 + 512 + h*64;
  const bf16_t* vtb = vT + ((size_t)(b*8 + h)*64)*2048 + kvb;
  // Q fragments direct from global (pre-scaled in qkv); uncoalesced but once
  const bf16_t* qp = qkv + (rbase + q0 + w*16 + lq)*1024 + h*64 + hi*8;
  bf16x8 aq0 = *(const bf16x8*)qp;
  bf16x8 aq1 = *(const bf16x8*)(qp + 32);
  // prologue: stage tile 0 into buf 0, full drain once
  gload_lds16(kb + (size_t)(kvb + rb0 + srow)*1024 + schunk, &Ks[0][rb0*64]);
  gload_lds16(kb + (size_t)(kvb + rb1 + srow)*1024 + schunk, &Ks[0][rb1*64]);
  gload_lds16(vtb + (size_t)(rb0 + srow)*2048 + schunk, &Vs[0][rb0*64]);
  gload_lds16(vtb + (size_t)(rb1 + srow)*2048 + schunk, &Vs[0][rb1*64]);
  asm volatile("s_waitcnt vmcnt(0)" ::: "memory");
  __builtin_amdgcn_s_barrier();

  int pw = w * 16 * 72;
  f32x4 accO[4] = {};
  f32x4 lacc = {};
  bf16x8 ones;
  #pragma unroll
  for (int e = 0; e < 8; e++) ones[e] = (bf16_t)1.0f;
  int swz = (lq & 7) << 3;

  for (int tt = 0; tt < NT; ++tt) {
    int cur = tt & 1;
    if (tt < NT-1) {
      // issue stage(t+1) into buf[cur^1]; gate stage(t) (<=4 older outstanding)
      int kv1 = kvb + (tt + 1) * 64;
      gload_lds16(kb + (size_t)(kv1 + rb0 + srow)*1024 + schunk, &Ks[cur^1][rb0*64]);
      gload_lds16(kb + (size_t)(kv1 + rb1 + srow)*1024 + schunk, &Ks[cur^1][rb1*64]);
      gload_lds16(vtb + (size_t)(rb0 + srow)*2048 + kv1 + schunk, &Vs[cur^1][rb0*64]);
      gload_lds16(vtb + (size_t)(rb1 + srow)*2048 + kv1 + schunk, &Vs[cur^1][rb1*64]);
      asm volatile("s_waitcnt vmcnt(4)" ::: "memory");
    } else {
      asm volatile("s_waitcnt vmcnt(0)" ::: "memory");
    }
    __builtin_amdgcn_s_barrier();   // buf[cur] valid for every wave
    // QK from Ks[cur] + aq regs; V fragments from Vs[cur]
    f32x4 s4[4] = {};
    bf16x8 vv[8];
    #pragma unroll
    for (int kk = 0; kk < 2; kk++) {
      int off = (kk*32 + hi*8) ^ swz;
      bf16x8 aq = kk ? aq1 : aq0;
      #pragma unroll
      for (int nf = 0; nf < 4; nf++) {
        bf16x8 bk = *(const bf16x8*)&Ks[cur][(nf*16 + lq)*64 + off];
        s4[nf] = __builtin_amdgcn_mfma_f32_16x16x32_bf16(aq, bk, s4[nf], 0, 0, 0);
        vv[kk*4+nf] = *(const bf16x8*)&Vs[cur][(nf*16 + lq)*64 + off];
      }
    }
    // P = 2^S -> Ps (wave-private; compiler orders write->read)
    #pragma unroll
    for (int nf = 0; nf < 4; nf++)
      #pragma unroll
      for (int r = 0; r < 4; r++)
        Ps[pw + (hi*4 + r)*72 + nf*16 + lq] = (bf16_t)fexp2(s4[nf][r]);
    // PV + row-sum (ones-MFMA)
    #pragma unroll
    for (int kk = 0; kk < 2; kk++) {
      bf16x8 pa = *(const bf16x8*)&Ps[pw + lq*72 + kk*32 + hi*8];
      lacc = __builtin_amdgcn_mfma_f32_16x16x32_bf16(pa, ones, lacc, 0, 0, 0);
      #pragma unroll
      for (int nf = 0; nf < 4; nf++)
        accO[nf] = __builtin_amdgcn_mfma_f32_16x16x32_bf16(pa, vv[kk*4+nf], accO[nf], 0, 0, 0);
    }
    if (tt < NT-1) {
      // all reads of buf[cur] retired before next iter's stage overwrites it
      asm volatile("s_waitcnt lgkmcnt(0)" ::: "memory");
      __builtin_amdgcn_s_barrier();
    }
  }
  // store bf16 partials (no normalize; combine does it)
  bf16_t* op = Ows + (size_t)sp*MROWS*512 + (rbase + q0 + w*16 + hi*4)*512 + h*64 + lq;
  #pragma unroll
  for (int nf = 0; nf < 4; nf++)
    #pragma unroll
    for (int r = 0; r < 4; r++)
      op[(size_t)r*512 + nf*16] = (bf16_t)accO[nf][r];
  if (lq == 0) {
    size_t rowb = rbase + q0 + w*16 + hi*4;
    #pragma unroll
    for (int r = 0; r < 4; r++)
      lws[(size_t)sp*MROWS*8 + (rowb + r)*8 + h] = lacc[r];
  }
}

// ---------------- combine: obuf = (sum_sp Ows) / (sum_sp lws) ----------------
__global__ __launch_bounds__(256) void combine_kernel(const bf16_t* __restrict__ Ows,
                                                      const float* __restrict__ lws,
                                                      bf16_t* __restrict__ obuf)
{
  int idx = blockIdx.x * 256 + threadIdx.x;   // 4096*512/4 = 524288 threads
  int row = idx >> 7, c4 = (idx & 127) * 4;
  bf16x4 o0 = *(const bf16x4*)&Ows[(size_t)row*512 + c4];
  bf16x4 o1 = *(const bf16x4*)&Ows[(size_t)(MROWS + row)*512 + c4];
  int h = c4 >> 6;
  float li = 1.0f / (lws[row*8 + h] + lws[MROWS*8 + row*8 + h]);
  bf16x4 o;
  #pragma unroll
  for (int i = 0; i < 4; i++) o[i] = (bf16_t)(((float)o0[i] + (float)o1[i]) * li);
  *(bf16x4*)&obuf[(size_t)row*512 + c4] = o;
}

// ---------------- gated gelu: ff = a * gelu(gate), g already has +bg ----------------
__global__ __launch_bounds__(256) void gelu_kernel(const float* __restrict__ g,
                                                   bf16_t* __restrict__ ff)
{
  int idx = blockIdx.x * 256 + threadIdx.x;  // 262144 threads, 4 outputs each
  int row = idx >> 6;
  int c = (idx & 63) * 4;
  const float* gr = g + (size_t)row*512;
  f32x4 a = *(const f32x4*)(gr + c);
  f32x4 u = *(const f32x4*)(gr + 256 + c);
  bf16x4 o4;
  #pragma unroll
  for (int i = 0; i < 4; i++) {
    float x = u[i];
    float tt = tanhf(0.7978845608f * x * (1.0f + 0.044715f * x * x));
    o4[i] = (bf16_t)(a[i] * 0.5f * x * (1.0f + tt));
  }
  *(bf16x4*)(ff + (size_t)row*256 + c) = o4;
}

// ---------------- launcher ----------------
extern "C" void kernel_launch(void* const* d_in, const int* in_sizes, int n_in,
                              void* d_out, int out_size, void* d_ws, size_t ws_size,
                              hipStream_t stream)
{
  const float* x     = (const float*)d_in[0];
  const float* gamma = (const float*)d_in[1];
  const float* beta  = (const float*)d_in[2];
  const float* Wq    = (const float*)d_in[3];
  const float* Wk    = (const float*)d_in[4];
  const float* Wv    = (const float*)d_in[5];
  const float* Wo    = (const float*)d_in[6];
  const float* bo    = (const float*)d_in[7];
  const float* Wg    = (const float*)d_in[8];
  const float* bg    = (const float*)d_in[9];
  const float* Wf    = (const float*)d_in[10];
  const float* bf    = (const float*)d_in[11];

  char* ws = (char*)d_ws;
  float*  xcur  = (float*)ws;                            // 0-8 MB   f32 [4096][512]
  bf16_t* hbuf  = (bf16_t*)(ws + (8u<<20));              // 8-12 MB  bf16 [4096][512]
  bf16_t* qkv   = (bf16_t*)(ws + (12u<<20));             // 12-20 MB bf16 [4096][1024] (q,k)
  bf16_t* vT    = (bf16_t*)(ws + (20u<<20));             // 20-24 MB bf16 [2][8][64][2048]
  bf16_t* obuf  = (bf16_t*)(ws + (24u<<20));             // 24-28 MB bf16 [4096][512]
  bf16_t* WqkvT = (bf16_t*)(ws + (28u<<20));             // 28-34 MB
  bf16_t* WoT   = (bf16_t*)(ws + (34u<<20));             // 34-36 MB
  bf16_t* WgT   = (bf16_t*)(ws + (36u<<20));             // 0.5 MB
  bf16_t* WfT   = (bf16_t*)(ws + (36u<<20) + (512u<<10));// 0.25 MB
  float*  lws   = (float*)(ws + (37u<<20));              // 37-37.25 MB f32 [2][4096][8]
  bf16_t* Ows   = (bf16_t*)(ws + (40u<<20));             // 40-48 MB bf16 [2][4096][512]
  float*  gbuf  = (float*)(ws + (48u<<20));              // 48-56 MB f32 [4096][512] (MLP)
  bf16_t* ffb   = obuf;                                  // reuse (o dead by MLP)

  const float QSCALE = 0.125f * 1.44269504f;  // fold 1/sqrt(CH) and log2(e) into q

  prep_kernel<<<dim3(16,16,18), 256, 0, stream>>>(Wq,Wk,Wv,Wo,Wg,Wf,WqkvT,WoT,WgT,WfT);
  hipMemcpyAsync(xcur, x, (size_t)MROWS*512*4, hipMemcpyDeviceToDevice, stream);

  for (int lay = 0; lay < 4; lay++) {
    ln_kernel<<<1024, 256, 0, stream>>>(xcur, gamma + lay*512, beta + lay*512, hbuf);
    gemm_bt<0,64,12><<<768, 256, 0, stream>>>(hbuf, WqkvT + (size_t)lay*1536*512,
                                              1536, 512, qkv, vT, nullptr, nullptr, QSCALE);
    attn_kernel<<<1024, 256, 0, stream>>>(qkv, vT, Ows, lws);
    combine_kernel<<<2048, 256, 0, stream>>>(Ows, lws, obuf);
    gemm_bt<1,64,4><<<256, 256, 0, stream>>>(obuf, WoT + (size_t)lay*512*512,
                                             512, 512, xcur, nullptr, bo + lay*512, xcur, 1.0f);
  }
  ln_kernel<<<1024, 256, 0, stream>>>(xcur, gamma + 4*512, beta + 4*512, hbuf);
  gemm_bt<2,64,4><<<256, 256, 0, stream>>>(hbuf, WgT, 512, 512, gbuf, nullptr, bg, nullptr, 1.0f);
  gelu_kernel<<<1024, 256, 0, stream>>>(gbuf, ffb);
  gemm_bt<1,64,4><<<256, 256, 0, stream>>>(ffb, WfT, 512, 256, d_out, nullptr, bf, xcur, 1.0f);
}

// Round 10
// 357.430 us; speedup vs baseline: 1.4512x; 1.1244x over previous
//
#include <hip/hip_runtime.h>
#include <hip/hip_bf16.h>

// Basic_Transformer on MI355X (gfx950): bf16 MFMA pipeline.
// B=2 S=2048 C=512 L=4 H=8 CH=64 OD=256; rows M = B*S = 4096.

typedef __bf16 bf16_t;
typedef __attribute__((ext_vector_type(8))) __bf16 bf16x8;
typedef __attribute__((ext_vector_type(4))) __bf16 bf16x4;
typedef __attribute__((ext_vector_type(4))) float f32x4;

#define MROWS 4096
#define KVSPLIT 2
#define NT 16   // (2048/KVSPLIT)/64 kv tiles per split

static __device__ __forceinline__ void gload_lds16(const void* g, void* l) {
  __builtin_amdgcn_global_load_lds((const __attribute__((address_space(1))) void*)g,
                                   (__attribute__((address_space(3))) void*)l, 16, 0, 0);
}
static __device__ __forceinline__ float fexp2(float x) {
  float r;
  asm("v_exp_f32 %0, %1" : "=v"(r) : "v"(x));
  return r;
}

// ---------------- layernorm: one wave per row (64 lanes x 8 f32) ----------------
__global__ __launch_bounds__(256) void ln_kernel(const float* __restrict__ xin,
    const float* __restrict__ gamma, const float* __restrict__ beta,
    bf16_t* __restrict__ hout)
{
  int w = threadIdx.x >> 6, l = threadIdx.x & 63;
  int row = blockIdx.x * 4 + w;
  const float* xr = xin + (size_t)row * 512 + l * 8;
  f32x4 a = *(const f32x4*)xr;
  f32x4 b2 = *(const f32x4*)(xr + 4);
  float s = a[0]+a[1]+a[2]+a[3]+b2[0]+b2[1]+b2[2]+b2[3];
  #pragma unroll
  for (int m = 1; m < 64; m <<= 1) s += __shfl_xor(s, m, 64);
  float mu = s * (1.0f/512.0f);
  float vs = 0.f;
  #pragma unroll
  for (int i = 0; i < 4; i++) { float d = a[i]-mu; vs += d*d; d = b2[i]-mu; vs += d*d; }
  #pragma unroll
  for (int m = 1; m < 64; m <<= 1) vs += __shfl_xor(vs, m, 64);
  float rstd = rsqrtf(vs * (1.0f/512.0f) + 1e-5f);
  const float* gp = gamma + l*8;
  const float* bp = beta + l*8;
  f32x4 g0 = *(const f32x4*)gp, g1 = *(const f32x4*)(gp+4);
  f32x4 p0 = *(const f32x4*)bp, p1 = *(const f32x4*)(bp+4);
  bf16x8 h;
  #pragma unroll
  for (int i = 0; i < 4; i++) {
    h[i]   = (bf16_t)((a[i]-mu)*rstd*g0[i] + p0[i]);
    h[4+i] = (bf16_t)((b2[i]-mu)*rstd*g1[i] + p1[i]);
  }
  *(bf16x8*)(hout + (size_t)row*512 + l*8) = h;
}

// ---------------- weight transpose + cast: [K][N] f32 -> [N][K] bf16 ----------------
__global__ __launch_bounds__(256) void prep_kernel(
    const float* __restrict__ Wq, const float* __restrict__ Wk, const float* __restrict__ Wv,
    const float* __restrict__ Wo, const float* __restrict__ Wg, const float* __restrict__ Wf,
    bf16_t* __restrict__ WqkvT, bf16_t* __restrict__ WoT,
    bf16_t* __restrict__ WgT, bf16_t* __restrict__ WfT)
{
  __shared__ float tile[32][33];
  int z = blockIdx.z;
  const float* src; bf16_t* dst; int K = 512, N = 512;
  if (z < 12) {
    int lay = z & 3, which = z >> 2;  // 0..3:Wq 4..7:Wk 8..11:Wv
    src = (which == 0 ? Wq : which == 1 ? Wk : Wv) + (size_t)lay*512*512;
    dst = WqkvT + (size_t)lay*1536*512 + (size_t)which*512*512;
  } else if (z < 16) {
    src = Wo + (size_t)(z-12)*512*512;
    dst = WoT + (size_t)(z-12)*512*512;
  } else if (z == 16) { src = Wg; dst = WgT; }
  else { src = Wf; dst = WfT; K = 256; }
  int k0 = blockIdx.y*32, n0 = blockIdx.x*32;
  if (k0 >= K) return;  // uniform per block (Wf has K=256)
  int tx = threadIdx.x & 31, ty = threadIdx.x >> 5;
  #pragma unroll
  for (int j = 0; j < 4; j++)
    tile[ty + j*8][tx] = src[(size_t)(k0 + ty + j*8)*N + n0 + tx];
  __syncthreads();
  #pragma unroll
  for (int j = 0; j < 4; j++)
    dst[(size_t)(n0 + ty + j*8)*K + k0 + tx] = (bf16_t)tile[tx][ty + j*8];
}

// ---------------- GEMM: C[M x N] = A[M x K](bf16) * Bt[N x K](bf16)^T ----------------
// BM x 128 tile, BK=64, 4 waves (2x2 of BM/2 x 64), 16x16x32 bf16 MFMA.
// 1-D grid (NX * ny blocks) with XCD-aware swizzle.
// EPI 0: QKV. cols<512 (q) scaled by qscale -> qkv[row][1024]; cols 512..1023 (k)
//        plain -> qkv; cols>=1024 (v) -> vT[b][h][ch][2048] (pre-transposed).
// EPI 1: f32 out + bias + resid.  EPI 2: f32 out + bias.
template<int EPI, int BM, int NX>
__global__ __launch_bounds__(256) void gemm_bt(
    const bf16_t* __restrict__ A, const bf16_t* __restrict__ Bt,
    int N, int K,
    void* __restrict__ Cout, bf16_t* __restrict__ vTout,
    const float* __restrict__ bias, const float* __restrict__ resid, float qscale)
{
  __shared__ bf16_t As[BM*64];
  __shared__ bf16_t Bs[128*64];
  constexpr int MF = BM/32;              // M-fragments per wave (128->4, 64->2)
  int cpx = gridDim.x >> 3;
  int logical = (blockIdx.x & 7) * cpx + (blockIdx.x >> 3);
  int bx = logical % NX, by = logical / NX;
  int t = threadIdx.x, w = t >> 6, l = t & 63;
  int tm = by * BM, tn = bx * 128;
  int wm = (w >> 1) * (BM/2), wn = (w & 1) * 64;
  f32x4 acc[MF][4] = {};
  int srow = l >> 3;                    // staging: 8 rows per 1KB inst
  int schunk = ((l & 7) ^ srow) * 8;    // XOR-swizzle via pre-swizzled global source
  for (int k0 = 0; k0 < K; k0 += 64) {
    __syncthreads();
    #pragma unroll
    for (int i = 0; i < BM/32; i++) {
      int rb = i*32 + w*8;
      gload_lds16(A + (size_t)(tm + rb + srow)*K + k0 + schunk, &As[rb*64]);
    }
    #pragma unroll
    for (int i = 0; i < 4; i++) {
      int rb = i*32 + w*8;
      gload_lds16(Bt + (size_t)(tn + rb + srow)*K + k0 + schunk, &Bs[rb*64]);
    }
    __syncthreads();
    #pragma unroll
    for (int kk = 0; kk < 2; kk++) {
      bf16x8 af[MF], bfr[4];
      #pragma unroll
      for (int mf = 0; mf < MF; mf++) {
        int row = wm + mf*16 + (l & 15);
        int off = (kk*32 + (l >> 4)*8) ^ ((row & 7) << 3);
        af[mf] = *(const bf16x8*)&As[row*64 + off];
      }
      #pragma unroll
      for (int nf = 0; nf < 4; nf++) {
        int row = wn + nf*16 + (l & 15);
        int off = (kk*32 + (l >> 4)*8) ^ ((row & 7) << 3);
        bfr[nf] = *(const bf16x8*)&Bs[row*64 + off];
      }
      #pragma unroll
      for (int mf = 0; mf < MF; mf++)
        #pragma unroll
        for (int nf = 0; nf < 4; nf++)
          acc[mf][nf] = __builtin_amdgcn_mfma_f32_16x16x32_bf16(af[mf], bfr[nf], acc[mf][nf], 0, 0, 0);
    }
  }
  int colb = tn + wn + (l & 15);
  int rowb = tm + wm + ((l >> 4) << 2);
  if (EPI == 0 && tn >= 1024) {
    // v region -> vT[b][h][ch][2048], vectorized over 4 consecutive s
    #pragma unroll
    for (int mf = 0; mf < MF; mf++)
      #pragma unroll
      for (int nf = 0; nf < 4; nf++) {
        int col = colb + nf*16;
        int hh = (col - 1024) >> 6, ch = (col - 1024) & 63;
        int row = rowb + mf*16;
        int bb = row >> 11, sdx = row & 2047;
        bf16x4 pk;
        #pragma unroll
        for (int r = 0; r < 4; r++) pk[r] = (bf16_t)acc[mf][nf][r];
        *(bf16x4*)&vTout[(((size_t)bb*8 + hh)*64 + ch)*2048 + sdx] = pk;
      }
    return;
  }
  #pragma unroll
  for (int mf = 0; mf < MF; mf++)
    #pragma unroll
    for (int nf = 0; nf < 4; nf++)
      #pragma unroll
      for (int r = 0; r < 4; r++) {
        int row = rowb + mf*16 + r;
        int col = colb + nf*16;
        float v = acc[mf][nf][r];
        if (EPI == 0) {
          if (col < 512) v *= qscale;
          ((bf16_t*)Cout)[(size_t)row*1024 + col] = (bf16_t)v;
        } else if (EPI == 1) {
          ((float*)Cout)[(size_t)row*N + col] = v + bias[col] + resid[(size_t)row*N + col];
        } else {
          ((float*)Cout)[(size_t)row*N + col] = v + bias[col];
        }
      }
}

// ---------------- fused flash attention (no-max softmax, KV-split partials) --------
// 1-D grid 512, XCD-swizzled: each (h,b,sp) group's 16 q0-blocks share one XCD.
// 256 threads = 4 waves; wave w owns 32 q-rows (w*32..+31, two 16-row blocks) —
// doubles MFMA per K/V LDS byte vs 16-row waves (LDS-throughput bound, r9 PM).
// qkv: [B*S][1024] bf16: q cols 0..511 (pre-scaled by 0.125*log2e), k 512..1023.
// vT:  [B][H][64 ch][2048 s] bf16.
// K and V double-buffered in LDS; stage(t+1) at tile top, counted vmcnt(4).
// Partials: Ows bf16 [sp][4096][512], lws f32 [sp][4096][8].
__global__ __launch_bounds__(256) void attn_kernel(const bf16_t* __restrict__ qkv,
                                                   const bf16_t* __restrict__ vT,
                                                   bf16_t* __restrict__ Ows,
                                                   float* __restrict__ lws)
{
  __shared__ bf16_t Ks[2][64*64];   // K tile [kv][ch] dbuf, swizzled
  __shared__ bf16_t Vs[2][64*64];   // V^T tile [ch][kv] dbuf, swizzled
  __shared__ bf16_t Ps[4*32*72];    // per-wave P (32 q-rows), stride 72
  int t = threadIdx.x, w = t >> 6, l = t & 63;
  // XCD swizzle: 512 blocks, 64/XCD; group = (h,b,sp) = 16 blocks, 4 groups/XCD.
  int logical = (blockIdx.x & 7) * 64 + (blockIdx.x >> 3);
  int q0 = (logical & 15) * 128;
  int group = logical >> 4;            // 0..31
  int h = group & 7;
  int bz = group >> 3;
  int b = bz >> 1, sp = bz & 1;
  size_t rbase = (size_t)b * 2048;
  int kvb = sp * (2048/KVSPLIT);
  int lq = l & 15, hi = l >> 4;
  int srow = l >> 3;
  int schunk = ((l & 7) ^ srow) * 8;
  int rb0 = w*16, rb1 = w*16 + 8;
  const bf16_t* kb  = qkv + rbase*1024 + 512 + h*64;
  const bf16_t* vtb = vT + ((size_t)(b*8 + h)*64)*2048 + kvb;
  // Q fragments (2 q-blocks x 2 kk) direct from global; uncoalesced but once
  const bf16_t* qp = qkv + (rbase + q0 + w*32 + lq)*1024 + h*64 + hi*8;
  bf16x8 aq[2][2];
  aq[0][0] = *(const bf16x8*)qp;
  aq[0][1] = *(const bf16x8*)(qp + 32);
  aq[1][0] = *(const bf16x8*)(qp + 16*1024);
  aq[1][1] = *(const bf16x8*)(qp + 16*1024 + 32);
  // prologue: stage tile 0 into buf 0, full drain once
  gload_lds16(kb + (size_t)(kvb + rb0 + srow)*1024 + schunk, &Ks[0][rb0*64]);
  gload_lds16(kb + (size_t)(kvb + rb1 + srow)*1024 + schunk, &Ks[0][rb1*64]);
  gload_lds16(vtb + (size_t)(rb0 + srow)*2048 + schunk, &Vs[0][rb0*64]);
  gload_lds16(vtb + (size_t)(rb1 + srow)*2048 + schunk, &Vs[0][rb1*64]);
  asm volatile("s_waitcnt vmcnt(0)" ::: "memory");
  __builtin_amdgcn_s_barrier();

  int pw = w * 32 * 72;
  f32x4 accO[2][4] = {};
  f32x4 lacc[2] = {};
  bf16x8 ones;
  #pragma unroll
  for (int e = 0; e < 8; e++) ones[e] = (bf16_t)1.0f;
  int swz = (lq & 7) << 3;

  for (int tt = 0; tt < NT; ++tt) {
    int cur = tt & 1;
    if (tt < NT-1) {
      // issue stage(t+1) into buf[cur^1]; gate stage(t) (<=4 older outstanding)
      int kv1 = kvb + (tt + 1) * 64;
      gload_lds16(kb + (size_t)(kv1 + rb0 + srow)*1024 + schunk, &Ks[cur^1][rb0*64]);
      gload_lds16(kb + (size_t)(kv1 + rb1 + srow)*1024 + schunk, &Ks[cur^1][rb1*64]);
      gload_lds16(vtb + (size_t)(rb0 + srow)*2048 + kv1 + schunk, &Vs[cur^1][rb0*64]);
      gload_lds16(vtb + (size_t)(rb1 + srow)*2048 + kv1 + schunk, &Vs[cur^1][rb1*64]);
      asm volatile("s_waitcnt vmcnt(4)" ::: "memory");
    } else {
      asm volatile("s_waitcnt vmcnt(0)" ::: "memory");
    }
    __builtin_amdgcn_s_barrier();   // buf[cur] valid for every wave
    // QK: each K fragment feeds BOTH q-blocks (halves K reads per MFMA)
    f32x4 s4[2][4] = {};
    #pragma unroll
    for (int kk = 0; kk < 2; kk++) {
      int off = (kk*32 + hi*8) ^ swz;
      #pragma unroll
      for (int nf = 0; nf < 4; nf++) {
        bf16x8 bk = *(const bf16x8*)&Ks[cur][(nf*16 + lq)*64 + off];
        s4[0][nf] = __builtin_amdgcn_mfma_f32_16x16x32_bf16(aq[0][kk], bk, s4[0][nf], 0, 0, 0);
        s4[1][nf] = __builtin_amdgcn_mfma_f32_16x16x32_bf16(aq[1][kk], bk, s4[1][nf], 0, 0, 0);
      }
    }
    // P = 2^S -> Ps (wave-private; compiler orders write->read)
    #pragma unroll
    for (int qb = 0; qb < 2; qb++)
      #pragma unroll
      for (int nf = 0; nf < 4; nf++)
        #pragma unroll
        for (int r = 0; r < 4; r++)
          Ps[pw + (qb*16 + hi*4 + r)*72 + nf*16 + lq] = (bf16_t)fexp2(s4[qb][nf][r]);
    // V fragments (shared across q-blocks)
    bf16x8 vv[8];
    #pragma unroll
    for (int kk = 0; kk < 2; kk++)
      #pragma unroll
      for (int nf = 0; nf < 4; nf++)
        vv[kk*4+nf] = *(const bf16x8*)&Vs[cur][(nf*16 + lq)*64 + ((kk*32 + hi*8) ^ swz)];
    // PV + row-sum (ones-MFMA)
    #pragma unroll
    for (int qb = 0; qb < 2; qb++)
      #pragma unroll
      for (int kk = 0; kk < 2; kk++) {
        bf16x8 pa = *(const bf16x8*)&Ps[pw + (qb*16 + lq)*72 + kk*32 + hi*8];
        lacc[qb] = __builtin_amdgcn_mfma_f32_16x16x32_bf16(pa, ones, lacc[qb], 0, 0, 0);
        #pragma unroll
        for (int nf = 0; nf < 4; nf++)
          accO[qb][nf] = __builtin_amdgcn_mfma_f32_16x16x32_bf16(pa, vv[kk*4+nf], accO[qb][nf], 0, 0, 0);
      }
    if (tt < NT-1) {
      // all reads of buf[cur] retired before next iter's stage overwrites it
      asm volatile("s_waitcnt lgkmcnt(0)" ::: "memory");
      __builtin_amdgcn_s_barrier();
    }
  }
  // store bf16 partials (no normalize; combine does it)
  #pragma unroll
  for (int qb = 0; qb < 2; qb++) {
    bf16_t* op = Ows + (size_t)sp*MROWS*512
               + (rbase + q0 + w*32 + qb*16 + hi*4)*512 + h*64 + lq;
    #pragma unroll
    for (int nf = 0; nf < 4; nf++)
      #pragma unroll
      for (int r = 0; r < 4; r++)
        op[(size_t)r*512 + nf*16] = (bf16_t)accO[qb][nf][r];
    if (lq == 0) {
      size_t rowb = rbase + q0 + w*32 + qb*16 + hi*4;
      #pragma unroll
      for (int r = 0; r < 4; r++)
        lws[(size_t)sp*MROWS*8 + (rowb + r)*8 + h] = lacc[qb][r];
    }
  }
}

// ---------------- combine: obuf = (sum_sp Ows) / (sum_sp lws) ----------------
__global__ __launch_bounds__(256) void combine_kernel(const bf16_t* __restrict__ Ows,
                                                      const float* __restrict__ lws,
                                                      bf16_t* __restrict__ obuf)
{
  int idx = blockIdx.x * 256 + threadIdx.x;   // 4096*512/4 = 524288 threads
  int row = idx >> 7, c4 = (idx & 127) * 4;
  bf16x4 o0 = *(const bf16x4*)&Ows[(size_t)row*512 + c4];
  bf16x4 o1 = *(const bf16x4*)&Ows[(size_t)(MROWS + row)*512 + c4];
  int h = c4 >> 6;
  float li = 1.0f / (lws[row*8 + h] + lws[MROWS*8 + row*8 + h]);
  bf16x4 o;
  #pragma unroll
  for (int i = 0; i < 4; i++) o[i] = (bf16_t)(((float)o0[i] + (float)o1[i]) * li);
  *(bf16x4*)&obuf[(size_t)row*512 + c4] = o;
}

// ---------------- gated gelu: ff = a * gelu(gate), g already has +bg ----------------
__global__ __launch_bounds__(256) void gelu_kernel(const float* __restrict__ g,
                                                   bf16_t* __restrict__ ff)
{
  int idx = blockIdx.x * 256 + threadIdx.x;  // 262144 threads, 4 outputs each
  int row = idx >> 6;
  int c = (idx & 63) * 4;
  const float* gr = g + (size_t)row*512;
  f32x4 a = *(const f32x4*)(gr + c);
  f32x4 u = *(const f32x4*)(gr + 256 + c);
  bf16x4 o4;
  #pragma unroll
  for (int i = 0; i < 4; i++) {
    float x = u[i];
    float tt = tanhf(0.7978845608f * x * (1.0f + 0.044715f * x * x));
    o4[i] = (bf16_t)(a[i] * 0.5f * x * (1.0f + tt));
  }
  *(bf16x4*)(ff + (size_t)row*256 + c) = o4;
}

// ---------------- launcher ----------------
extern "C" void kernel_launch(void* const* d_in, const int* in_sizes, int n_in,
                              void* d_out, int out_size, void* d_ws, size_t ws_size,
                              hipStream_t stream)
{
  const float* x     = (const float*)d_in[0];
  const float* gamma = (const float*)d_in[1];
  const float* beta  = (const float*)d_in[2];
  const float* Wq    = (const float*)d_in[3];
  const float* Wk    = (const float*)d_in[4];
  const float* Wv    = (const float*)d_in[5];
  const float* Wo    = (const float*)d_in[6];
  const float* bo    = (const float*)d_in[7];
  const float* Wg    = (const float*)d_in[8];
  const float* bg    = (const float*)d_in[9];
  const float* Wf    = (const float*)d_in[10];
  const float* bf    = (const float*)d_in[11];

  char* ws = (char*)d_ws;
  float*  xcur  = (float*)ws;                            // 0-8 MB   f32 [4096][512]
  bf16_t* hbuf  = (bf16_t*)(ws + (8u<<20));              // 8-12 MB  bf16 [4096][512]
  bf16_t* qkv   = (bf16_t*)(ws + (12u<<20));             // 12-20 MB bf16 [4096][1024] (q,k)
  bf16_t* vT    = (bf16_t*)(ws + (20u<<20));             // 20-24 MB bf16 [2][8][64][2048]
  bf16_t* obuf  = (bf16_t*)(ws + (24u<<20));             // 24-28 MB bf16 [4096][512]
  bf16_t* WqkvT = (bf16_t*)(ws + (28u<<20));             // 28-34 MB
  bf16_t* WoT   = (bf16_t*)(ws + (34u<<20));             // 34-36 MB
  bf16_t* WgT   = (bf16_t*)(ws + (36u<<20));             // 0.5 MB
  bf16_t* WfT   = (bf16_t*)(ws + (36u<<20) + (512u<<10));// 0.25 MB
  float*  lws   = (float*)(ws + (37u<<20));              // 37-37.25 MB f32 [2][4096][8]
  bf16_t* Ows   = (bf16_t*)(ws + (40u<<20));             // 40-48 MB bf16 [2][4096][512]
  float*  gbuf  = (float*)(ws + (48u<<20));              // 48-56 MB f32 [4096][512] (MLP)
  bf16_t* ffb   = obuf;                                  // reuse (o dead by MLP)

  const float QSCALE = 0.125f * 1.44269504f;  // fold 1/sqrt(CH) and log2(e) into q

  prep_kernel<<<dim3(16,16,18), 256, 0, stream>>>(Wq,Wk,Wv,Wo,Wg,Wf,WqkvT,WoT,WgT,WfT);
  hipMemcpyAsync(xcur, x, (size_t)MROWS*512*4, hipMemcpyDeviceToDevice, stream);

  for (int lay = 0; lay < 4; lay++) {
    ln_kernel<<<1024, 256, 0, stream>>>(xcur, gamma + lay*512, beta + lay*512, hbuf);
    gemm_bt<0,64,12><<<768, 256, 0, stream>>>(hbuf, WqkvT + (size_t)lay*1536*512,
                                              1536, 512, qkv, vT, nullptr, nullptr, QSCALE);
    attn_kernel<<<512, 256, 0, stream>>>(qkv, vT, Ows, lws);
    combine_kernel<<<2048, 256, 0, stream>>>(Ows, lws, obuf);
    gemm_bt<1,64,4><<<256, 256, 0, stream>>>(obuf, WoT + (size_t)lay*512*512,
                                             512, 512, xcur, nullptr, bo + lay*512, xcur, 1.0f);
  }
  ln_kernel<<<1024, 256, 0, stream>>>(xcur, gamma + 4*512, beta + 4*512, hbuf);
  gemm_bt<2,64,4><<<256, 256, 0, stream>>>(hbuf, WgT, 512, 512, gbuf, nullptr, bg, nullptr, 1.0f);
  gelu_kernel<<<1024, 256, 0, stream>>>(gbuf, ffb);
  gemm_bt<1,64,4><<<256, 256, 0, stream>>>(ffb, WfT, 512, 256, d_out, nullptr, bf, xcur, 1.0f);
}